// Round 6
// baseline (979.604 us; speedup 1.0000x reference)
//
#include <hip/hip_runtime.h>
#include <stdint.h>

typedef short v8s __attribute__((ext_vector_type(8)));   // 8 bf16 (4 VGPRs)
typedef float v4f __attribute__((ext_vector_type(4)));   // 16x16 C/D frag
// may_alias twins for the P LDS round-trip: strips TBAA so the P ds_write ->
// ds_read same-wave dependence is visible to alias analysis (round-3 hazard),
// while Ks/Vs/global accesses keep full scheduling freedom (round-4 lesson).
typedef short v8s_a __attribute__((ext_vector_type(8), may_alias));
typedef short v4s_a __attribute__((ext_vector_type(4), may_alias));

__device__ __forceinline__ unsigned short f2bf(float f) {
    union { float f; uint32_t u; } x; x.f = f;
    uint32_t r = (x.u + 0x7fffu + ((x.u >> 16) & 1u)) >> 16;
    return (unsigned short)r;
}
// packed f32x2 -> bf16x2 in one VALU op (gfx950 v_cvt_pk_bf16_f32, RNE)
__device__ __forceinline__ uint32_t cvt_pk_bf16(float lo, float hi) {
    uint32_t r;
    asm("v_cvt_pk_bf16_f32 %0, %1, %2" : "=v"(r) : "v"(lo), "v"(hi));
    return r;
}

#define QSCALE 0.18033688011112042f   /* 0.125 * log2(e) */
#define L2E    1.4426950408889634f    /* log2(e) — mask adds +1.0 to logits */
// sched_barrier mask: allow ALU|VALU|SALU|MFMA|VMEM|VMEM_READ|VMEM_WRITE to
// cross, block all DS (read+write). Orders the P LDS round-trip at the
// machine-scheduler level without serializing compute or global traffic.
#define SCHED_NO_DS 0x7F

// ---------------- fp32 -> bf16 cast (memory-bound) ----------------
__global__ __launch_bounds__(256) void cast_f32_bf16(const float* __restrict__ in,
                                                     unsigned short* __restrict__ out, int n) {
    int i = (blockIdx.x * 256 + threadIdx.x) * 4;
    const int stride = gridDim.x * 256 * 4;
    for (; i < n; i += stride) {
        float4 v = *(const float4*)(in + i);
        ushort4 o;
        o.x = f2bf(v.x); o.y = f2bf(v.y); o.z = f2bf(v.z); o.w = f2bf(v.w);
        *(ushort4*)(out + i) = o;
    }
}

// ---------------- NT GEMM: C[M,N] = A[M,K] * B[N,K]^T + bias ----------------
// 128x128 tile, BK=64, 4 waves (2x2 of 64x64), 16x16x32 bf16 MFMA,
// global_load_lds width-16 staging, XOR-swizzled 16B chunks.
// VSPLIT: cols >= 2048 (V third of QKV) stored TRANSPOSED to vt[col-2048][M];
//         cols < 1024 (Q third) are pre-scaled by QSCALE so attention's
//         softmax can use exp2(s + bias) with no per-element multiply.
template <bool OUT_F32, bool VSPLIT>
__global__ __launch_bounds__(256) void gemm_nt(const unsigned short* __restrict__ A,
                                               const unsigned short* __restrict__ B,
                                               const float* __restrict__ bias,
                                               void* __restrict__ Cout,
                                               unsigned short* __restrict__ vt,
                                               int M, int N, int K, int ldc) {
    __shared__ unsigned short As[128 * 64];
    __shared__ unsigned short Bs[128 * 64];
    const int tid = threadIdx.x;
    const int wv = tid >> 6, lane = tid & 63;
    const int quad = lane >> 4, l16 = lane & 15;
    const int tiles_n = N >> 7;
    const int tm = blockIdx.x / tiles_n, tn = blockIdx.x - tm * tiles_n;
    const int m0 = tm << 7, n0 = tn << 7;
    const int wr = (wv >> 1) * 64, wc = (wv & 1) * 64;

    v4f acc[4][4] = {};

    for (int k0 = 0; k0 < K; k0 += 64) {
        __syncthreads();
#pragma unroll
        for (int j = 0; j < 4; ++j) {
            const int cb = (wv * 4 + j) * 64;
            const int cl = cb + lane;
            const int row = cl >> 3;
            const int kc = (cl & 7) ^ (row & 7);
            const unsigned short* ga = A + (size_t)(m0 + row) * K + k0 + kc * 8;
            const unsigned short* gb = B + (size_t)(n0 + row) * K + k0 + kc * 8;
            __builtin_amdgcn_global_load_lds(
                (const __attribute__((address_space(1))) unsigned int*)ga,
                (__attribute__((address_space(3))) unsigned int*)(As + cb * 8), 16, 0, 0);
            __builtin_amdgcn_global_load_lds(
                (const __attribute__((address_space(1))) unsigned int*)gb,
                (__attribute__((address_space(3))) unsigned int*)(Bs + cb * 8), 16, 0, 0);
        }
        __syncthreads();
#pragma unroll
        for (int ks = 0; ks < 2; ++ks) {
            v8s af[4], bf[4];
#pragma unroll
            for (int mt = 0; mt < 4; ++mt) {
                const int row = wr + mt * 16 + l16;
                const int ch = row * 8 + ((ks * 4 + quad) ^ (row & 7));
                af[mt] = *(const v8s*)(As + ch * 8);
            }
#pragma unroll
            for (int nt = 0; nt < 4; ++nt) {
                const int row = wc + nt * 16 + l16;
                const int ch = row * 8 + ((ks * 4 + quad) ^ (row & 7));
                bf[nt] = *(const v8s*)(Bs + ch * 8);
            }
#pragma unroll
            for (int mt = 0; mt < 4; ++mt)
#pragma unroll
                for (int nt = 0; nt < 4; ++nt)
                    acc[mt][nt] = __builtin_amdgcn_mfma_f32_16x16x32_bf16(
                        af[mt], bf[nt], acc[mt][nt], 0, 0, 0);
        }
    }
#pragma unroll
    for (int nt = 0; nt < 4; ++nt) {
        const int col = n0 + wc + nt * 16 + l16;
        const float bv = bias[col];
        if (VSPLIT && col >= 2048) {
#pragma unroll
            for (int mt = 0; mt < 4; ++mt) {
                const int rowb = m0 + wr + mt * 16 + quad * 4;
                ushort4 o;
                o.x = f2bf(acc[mt][nt][0] + bv);
                o.y = f2bf(acc[mt][nt][1] + bv);
                o.z = f2bf(acc[mt][nt][2] + bv);
                o.w = f2bf(acc[mt][nt][3] + bv);
                *(ushort4*)(vt + (size_t)(col - 2048) * M + rowb) = o;
            }
        } else {
            // Q columns carry the softmax scale folded in (exact same bf16
            // rounding class as unscaled; K columns untouched).
            const float scl = (VSPLIT && col < 1024) ? QSCALE : 1.0f;
#pragma unroll
            for (int mt = 0; mt < 4; ++mt) {
                const int rowb = m0 + wr + mt * 16 + quad * 4;
#pragma unroll
                for (int r = 0; r < 4; ++r) {
                    if (OUT_F32)
                        ((float*)Cout)[(size_t)(rowb + r) * ldc + col] = acc[mt][nt][r] + bv;
                    else
                        ((unsigned short*)Cout)[(size_t)(rowb + r) * ldc + col] =
                            f2bf((acc[mt][nt][r] + bv) * scl);
                }
            }
        }
    }
}

// ---------------- windowed attention (S^T orientation) ----------------
// qk: [R,2048] bf16 (Q(pre-scaled by 0.125*log2e)|K). Vt: [1024][R] bf16 (V^T).
// O: [R,1024] bf16.
// Block = (window, head, 128-row q-block); wave = 32 q-rows (2 subtiles).
// S^T = K*Q^T via MFMA(A=K-frag, B=Q-frag): C-layout puts 4 CONSECUTIVE keys
// (quad*4+r) of one q-row (l16) in each lane -> P written as packed ds_write_b64
// straight into A-operand layout. K-frag LDS reads shared across both subtiles.
// Softmax: e = exp2(s + mask) via RAW v_exp_f32 (__builtin_amdgcn_exp2f);
// args bounded (|s|<~4), far from the subnormal guard range, so exact here.
// mask = L2E if key>qrow else 0, branchless cmp+cndmask (STRAIGHT-LINE — a
// wave-uniform scalar branch here spilled sf[2][8] to scratch in round 1).
// P packed to bf16 via v_cvt_pk_bf16_f32 (1 op/pair).
//
// ORDERING (round 3 fail / round 4 over-fix / round 5 compile-fail): the P
// store->load same-wave dependence was invisible to TBAA (uint2 store vs v8s
// load) and got hoisted once exp became one instruction. Full "memory"
// clobbers fixed it but serialized Ks/Vs reads + spilled (~59MB scratch);
// an "+m"(LDS) scoped fence doesn't match in the AMDGPU backend. Fix now:
//  (a) may_alias vector types on P accesses -> BasicAA sees a true overlap
//      dependence on the Ps object only; and
//  (b) sched_barrier(0x7F) at the two points -> machine scheduler may move
//      ALU/MFMA/VMEM across but NO DS ops. Zero runtime cost.
//
// V-fragments (subtile-invariant) hoisted to registers once per k-tile:
// DS reads drop 56->40 b128/kt/wave. vreg loaded AFTER st=0 softmax so sf[0]
// is dead first: peak live ~ sf[1]32+vreg64+oacc32+qf16 ~ 160 VGPR.
// No online softmax (mask is +1.0 additive, scores bounded -> shift=0 exact).
__global__ __launch_bounds__(256, 3) void attn_win(const unsigned short* __restrict__ qk,
                                                   const unsigned short* __restrict__ Vt,
                                                   unsigned short* __restrict__ O,
                                                   int W) {
    const int nkt = W >> 7;
    const int tid = threadIdx.x, wv = tid >> 6, lane = tid & 63;
    const int quad = lane >> 4, l16 = lane & 15;

    // block remap (global path): keep the 8 q-blocks of one (window,head) on one XCD
    int wh, qb;
    if (nkt == 8) {
        const int g = blockIdx.x;
        wh = (g >> 6) * 8 + (g & 7);     // window*16+head
        qb = (g >> 3) & 7;
    } else {
        wh = blockIdx.x; qb = 0;
    }
    const int winst = wh >> 4, head = wh & 15;
    const size_t rw = (size_t)winst * W;

    __shared__ unsigned short Ks[128 * 64];     // [key][8 chunks, XOR-swizzled]
    __shared__ unsigned short Vs[64 * 128];     // V^T tile [dh][16 chunks, XOR-swizzled]
    __shared__ unsigned short Ps[4 * 16 * 136]; // per-wave P [16 q-rows][128 keys + 8 pad]
    unsigned short* Pw = Ps + wv * 16 * 136;

    // Q frags (B-operand layout: lane&15 = q-row, quad*8+j = k), reused all k-tiles
    v8s qf[2][2];
#pragma unroll
    for (int st = 0; st < 2; ++st) {
        const size_t qrow = rw + (size_t)(qb * 128 + wv * 32 + st * 16 + l16);
        const unsigned short* qp = qk + qrow * 2048 + head * 64 + quad * 8;
        qf[st][0] = *(const v8s*)qp;
        qf[st][1] = *(const v8s*)(qp + 32);
    }

    float rsum[2] = {0.f, 0.f};   // row sum for q-row l16 (partial over this lane's keys)
    v4f oacc[2][4] = {};          // O C-layout: col(dh)=l16, row(q)=quad*4+r

    for (int kt = 0; kt < nkt; ++kt) {
        __syncthreads();
#pragma unroll
        for (int j = 0; j < 4; ++j) {           // stage K tile: 128 keys x 64 dh
            const int cb = (wv * 4 + j) * 64;
            const int cl = cb + lane;
            const int key = cl >> 3, c = cl & 7;
            const unsigned short* src = qk + (rw + (size_t)(kt * 128 + key)) * 2048
                                        + 1024 + head * 64 + ((c ^ (key & 7)) * 8);
            __builtin_amdgcn_global_load_lds(
                (const __attribute__((address_space(1))) unsigned int*)src,
                (__attribute__((address_space(3))) unsigned int*)(Ks + cb * 8), 16, 0, 0);
        }
#pragma unroll
        for (int j = 0; j < 4; ++j) {           // stage V^T tile: 64 dh x 128 keys
            const int cb = (wv * 4 + j) * 64;
            const int cl = cb + lane;
            const int dh = cl >> 4, c = cl & 15;
            const unsigned short* src = Vt + (size_t)(head * 64 + dh) * 16384
                                        + rw + (size_t)(kt * 128) + ((c ^ (dh & 7)) * 8);
            __builtin_amdgcn_global_load_lds(
                (const __attribute__((address_space(1))) unsigned int*)src,
                (__attribute__((address_space(3))) unsigned int*)(Vs + cb * 8), 16, 0, 0);
        }
        __syncthreads();

        // S^T for both subtiles, sharing every K-frag read
        v4f sf[2][8] = {};
#pragma unroll
        for (int nt = 0; nt < 8; ++nt) {
            const int krow = nt * 16 + l16;
#pragma unroll
            for (int ks = 0; ks < 2; ++ks) {
                const v8s kf = *(const v8s*)(Ks + krow * 64 + ((ks * 4 + quad) ^ (krow & 7)) * 8);
                sf[0][nt] = __builtin_amdgcn_mfma_f32_16x16x32_bf16(kf, qf[0][ks], sf[0][nt], 0, 0, 0);
                sf[1][nt] = __builtin_amdgcn_mfma_f32_16x16x32_bf16(kf, qf[1][ks], sf[1][nt], 0, 0, 0);
            }
        }

        v8s vreg[4][4];               // V-frags, subtile-invariant: loaded once per kt
#pragma unroll
        for (int st = 0; st < 2; ++st) {
            const int irow = qb * 128 + wv * 32 + st * 16 + l16;   // this lane's q-row
            float rl = 0.f;
#pragma unroll
            for (int nt = 0; nt < 8; ++nt) {
                const int jb = kt * 128 + nt * 16 + quad * 4;      // first key in this lane's 4
                float e[4];
#pragma unroll
                for (int r = 0; r < 4; ++r)
                    e[r] = __builtin_amdgcn_exp2f(sf[st][nt][r] + ((jb + r > irow) ? L2E : 0.0f));
                rl += (e[0] + e[1]) + (e[2] + e[3]);
                union { uint32_t u[2]; v4s_a s; } pu;
                pu.u[0] = cvt_pk_bf16(e[0], e[1]);
                pu.u[1] = cvt_pk_bf16(e[2], e[3]);
                *(v4s_a*)(Pw + l16 * 136 + nt * 16 + quad * 4) = pu.s;   // ds_write_b64
            }
            rsum[st] += rl;
            // fence: DS ops may not cross (P stores stay above P loads);
            // ALU/MFMA/VMEM flow freely.
            __builtin_amdgcn_sched_barrier(SCHED_NO_DS);
            if (st == 0) {            // load V-frags once, after sf[0] is dead
#pragma unroll
                for (int kk = 0; kk < 4; ++kk)
#pragma unroll
                    for (int dt = 0; dt < 4; ++dt) {
                        const int dh = dt * 16 + l16;
                        vreg[kk][dt] = *(const v8s*)(Vs + dh * 128 + ((kk * 4 + quad) ^ (dh & 7)) * 8);
                    }
            }
            // O += P V  (P read back in A-layout via may_alias type: true
            // dependence on the P stores above is visible to alias analysis)
#pragma unroll
            for (int kk = 0; kk < 4; ++kk) {
                const v8s pf = (v8s)(*(const v8s_a*)(Pw + l16 * 136 + kk * 32 + quad * 8));
#pragma unroll
                for (int dt = 0; dt < 4; ++dt)
                    oacc[st][dt] = __builtin_amdgcn_mfma_f32_16x16x32_bf16(pf, vreg[kk][dt], oacc[st][dt], 0, 0, 0);
            }
            // fence: next subtile's / k-tile's P stores may not hoist above these loads.
            __builtin_amdgcn_sched_barrier(SCHED_NO_DS);
        }
    }

    // reduce row sums across quads (row = l16), redistribute to C-layout rows, store
#pragma unroll
    for (int st = 0; st < 2; ++st) {
        float l = rsum[st];
        l += __shfl_xor(l, 16);
        l += __shfl_xor(l, 32);
        const float inv = 1.0f / l;              // inverse sum for q-row l16
#pragma unroll
        for (int r = 0; r < 4; ++r) {
            const float invr = __shfl(inv, quad * 4 + r);   // row quad*4+r's inverse
            const size_t row = rw + (size_t)(qb * 128 + wv * 32 + st * 16 + quad * 4 + r);
#pragma unroll
            for (int dt = 0; dt < 4; ++dt)
                O[row * 1024 + head * 64 + dt * 16 + l16] = f2bf(oacc[st][dt][r] * invr);
        }
    }
}

// ---------------- launcher ----------------
extern "C" void kernel_launch(void* const* d_in, const int* in_sizes, int n_in,
                              void* d_out, int out_size, void* d_ws, size_t ws_size,
                              hipStream_t stream) {
    const float* lqs    = (const float*)d_in[0];
    const float* gqs    = (const float*)d_in[1];
    const float* wl_in  = (const float*)d_in[2];
    const float* bl_in  = (const float*)d_in[3];
    const float* wl_out = (const float*)d_in[4];
    const float* bl_out = (const float*)d_in[5];
    const float* wg_in  = (const float*)d_in[6];
    const float* bg_in  = (const float*)d_in[7];
    const float* wg_out = (const float*)d_in[8];
    const float* bg_out = (const float*)d_in[9];

    char* ws = (char*)d_ws;                                       // total 176,160,768 B
    unsigned short* Xbf    = (unsigned short*)(ws);               // 33,554,432
    unsigned short* Obf    = (unsigned short*)(ws + 33554432);    // 33,554,432
    unsigned short* Winbf  = (unsigned short*)(ws + 67108864);    //  6,291,456
    unsigned short* Woutbf = (unsigned short*)(ws + 73400320);    //  2,097,152
    unsigned short* QKbf   = (unsigned short*)(ws + 75497472);    // 67,108,864  [R][2048]
    unsigned short* Vtbf   = (unsigned short*)(ws + 142606336);   // 33,554,432  [1024][R]

    const int R = 4 * 4096;   // 16384 rows (windows tile S contiguously)
    const int D = 1024;

    for (int path = 0; path < 2; ++path) {
        const float* x     = path == 0 ? lqs : gqs;
        const float* w_in  = path == 0 ? wl_in : wg_in;
        const float* b_in  = path == 0 ? bl_in : bg_in;
        const float* w_out = path == 0 ? wl_out : wg_out;
        const float* b_out = path == 0 ? bl_out : bg_out;
        const int W        = path == 0 ? 128 : 1024;
        float* outp = (float*)d_out + (size_t)path * R * D;

        hipLaunchKernelGGL(cast_f32_bf16, dim3(4096), dim3(256), 0, stream, x, Xbf, R * D);
        hipLaunchKernelGGL(cast_f32_bf16, dim3(3072), dim3(256), 0, stream, w_in, Winbf, 3 * D * D);
        hipLaunchKernelGGL(cast_f32_bf16, dim3(1024), dim3(256), 0, stream, w_out, Woutbf, D * D);
        // QKV projection: Q|K row-major (ldc=2048, Q pre-scaled), V transposed into Vtbf
        hipLaunchKernelGGL((gemm_nt<false, true>), dim3(128 * 24), dim3(256), 0, stream,
                           Xbf, Winbf, b_in, (void*)QKbf, Vtbf, R, 3 * D, D, 2048);
        hipLaunchKernelGGL(attn_win, dim3(2048), dim3(256), 0, stream, QKbf, Vtbf, Obf, W);
        // output projection -> fp32 d_out
        hipLaunchKernelGGL((gemm_nt<true, false>), dim3(128 * 8), dim3(256), 0, stream,
                           Obf, Woutbf, b_out, (void*)outp, (unsigned short*)nullptr,
                           R, D, D, 1024);
    }
}

// Round 7
// 804.111 us; speedup vs baseline: 1.2182x; 1.2182x over previous
//
#include <hip/hip_runtime.h>
#include <stdint.h>

typedef short v8s __attribute__((ext_vector_type(8)));   // 8 bf16 (4 VGPRs)
typedef float v4f __attribute__((ext_vector_type(4)));   // 16x16 C/D frag
// may_alias twins for the P LDS round-trip: strips TBAA so the P ds_write ->
// ds_read same-wave dependence is visible to alias analysis (round-3 hazard),
// while Ks/Vs/global accesses keep full scheduling freedom (round-4 lesson).
typedef short v8s_a __attribute__((ext_vector_type(8), may_alias));
typedef short v4s_a __attribute__((ext_vector_type(4), may_alias));

__device__ __forceinline__ unsigned short f2bf(float f) {
    union { float f; uint32_t u; } x; x.f = f;
    uint32_t r = (x.u + 0x7fffu + ((x.u >> 16) & 1u)) >> 16;
    return (unsigned short)r;
}
// packed f32x2 -> bf16x2 in one VALU op (gfx950 v_cvt_pk_bf16_f32, RNE)
__device__ __forceinline__ uint32_t cvt_pk_bf16(float lo, float hi) {
    uint32_t r;
    asm("v_cvt_pk_bf16_f32 %0, %1, %2" : "=v"(r) : "v"(lo), "v"(hi));
    return r;
}

#define QSCALE 0.18033688011112042f   /* 0.125 * log2(e) */
#define L2E    1.4426950408889634f    /* log2(e) — mask adds +1.0 to logits */
// sched_barrier mask: allow ALU|VALU|SALU|MFMA|VMEM to cross, block all DS
// (read+write). Orders the P LDS round-trip at the machine-scheduler level
// without serializing compute or global traffic. Proven correct in round 6.
#define SCHED_NO_DS 0x7F

// ---------------- fp32 -> bf16 cast (memory-bound) ----------------
__global__ __launch_bounds__(256) void cast_f32_bf16(const float* __restrict__ in,
                                                     unsigned short* __restrict__ out, int n) {
    int i = (blockIdx.x * 256 + threadIdx.x) * 4;
    const int stride = gridDim.x * 256 * 4;
    for (; i < n; i += stride) {
        float4 v = *(const float4*)(in + i);
        ushort4 o;
        o.x = f2bf(v.x); o.y = f2bf(v.y); o.z = f2bf(v.z); o.w = f2bf(v.w);
        *(ushort4*)(out + i) = o;
    }
}

// ---------------- NT GEMM: C[M,N] = A[M,K] * B[N,K]^T + bias ----------------
// 128x128 tile, BK=64, 4 waves (2x2 of 64x64), 16x16x32 bf16 MFMA,
// global_load_lds width-16 staging, XOR-swizzled 16B chunks.
// VSPLIT: cols >= 2048 (V third of QKV) stored TRANSPOSED to vt[col-2048][M];
//         cols < 1024 (Q third) are pre-scaled by QSCALE so attention's
//         softmax can use exp2(s + bias) with no per-element multiply.
template <bool OUT_F32, bool VSPLIT>
__global__ __launch_bounds__(256) void gemm_nt(const unsigned short* __restrict__ A,
                                               const unsigned short* __restrict__ B,
                                               const float* __restrict__ bias,
                                               void* __restrict__ Cout,
                                               unsigned short* __restrict__ vt,
                                               int M, int N, int K, int ldc) {
    __shared__ unsigned short As[128 * 64];
    __shared__ unsigned short Bs[128 * 64];
    const int tid = threadIdx.x;
    const int wv = tid >> 6, lane = tid & 63;
    const int quad = lane >> 4, l16 = lane & 15;
    const int tiles_n = N >> 7;
    const int tm = blockIdx.x / tiles_n, tn = blockIdx.x - tm * tiles_n;
    const int m0 = tm << 7, n0 = tn << 7;
    const int wr = (wv >> 1) * 64, wc = (wv & 1) * 64;

    v4f acc[4][4] = {};

    for (int k0 = 0; k0 < K; k0 += 64) {
        __syncthreads();
#pragma unroll
        for (int j = 0; j < 4; ++j) {
            const int cb = (wv * 4 + j) * 64;
            const int cl = cb + lane;
            const int row = cl >> 3;
            const int kc = (cl & 7) ^ (row & 7);
            const unsigned short* ga = A + (size_t)(m0 + row) * K + k0 + kc * 8;
            const unsigned short* gb = B + (size_t)(n0 + row) * K + k0 + kc * 8;
            __builtin_amdgcn_global_load_lds(
                (const __attribute__((address_space(1))) unsigned int*)ga,
                (__attribute__((address_space(3))) unsigned int*)(As + cb * 8), 16, 0, 0);
            __builtin_amdgcn_global_load_lds(
                (const __attribute__((address_space(1))) unsigned int*)gb,
                (__attribute__((address_space(3))) unsigned int*)(Bs + cb * 8), 16, 0, 0);
        }
        __syncthreads();
#pragma unroll
        for (int ks = 0; ks < 2; ++ks) {
            v8s af[4], bf[4];
#pragma unroll
            for (int mt = 0; mt < 4; ++mt) {
                const int row = wr + mt * 16 + l16;
                const int ch = row * 8 + ((ks * 4 + quad) ^ (row & 7));
                af[mt] = *(const v8s*)(As + ch * 8);
            }
#pragma unroll
            for (int nt = 0; nt < 4; ++nt) {
                const int row = wc + nt * 16 + l16;
                const int ch = row * 8 + ((ks * 4 + quad) ^ (row & 7));
                bf[nt] = *(const v8s*)(Bs + ch * 8);
            }
#pragma unroll
            for (int mt = 0; mt < 4; ++mt)
#pragma unroll
                for (int nt = 0; nt < 4; ++nt)
                    acc[mt][nt] = __builtin_amdgcn_mfma_f32_16x16x32_bf16(
                        af[mt], bf[nt], acc[mt][nt], 0, 0, 0);
        }
    }
#pragma unroll
    for (int nt = 0; nt < 4; ++nt) {
        const int col = n0 + wc + nt * 16 + l16;
        const float bv = bias[col];
        if (VSPLIT && col >= 2048) {
#pragma unroll
            for (int mt = 0; mt < 4; ++mt) {
                const int rowb = m0 + wr + mt * 16 + quad * 4;
                ushort4 o;
                o.x = f2bf(acc[mt][nt][0] + bv);
                o.y = f2bf(acc[mt][nt][1] + bv);
                o.z = f2bf(acc[mt][nt][2] + bv);
                o.w = f2bf(acc[mt][nt][3] + bv);
                *(ushort4*)(vt + (size_t)(col - 2048) * M + rowb) = o;
            }
        } else {
            // Q columns carry the softmax scale folded in (exact same bf16
            // rounding class as unscaled; K columns untouched).
            const float scl = (VSPLIT && col < 1024) ? QSCALE : 1.0f;
#pragma unroll
            for (int mt = 0; mt < 4; ++mt) {
                const int rowb = m0 + wr + mt * 16 + quad * 4;
#pragma unroll
                for (int r = 0; r < 4; ++r) {
                    if (OUT_F32)
                        ((float*)Cout)[(size_t)(rowb + r) * ldc + col] = acc[mt][nt][r] + bv;
                    else
                        ((unsigned short*)Cout)[(size_t)(rowb + r) * ldc + col] =
                            f2bf((acc[mt][nt][r] + bv) * scl);
                }
            }
        }
    }
}

// ---------------- windowed attention (S^T orientation) ----------------
// qk: [R,2048] bf16 (Q(pre-scaled by 0.125*log2e)|K). Vt: [1024][R] bf16 (V^T).
// O: [R,1024] bf16.
// Block = (window, head, 128-row q-block); wave = 32 q-rows (2 subtiles).
// S^T = K*Q^T via MFMA(A=K-frag, B=Q-frag): C-layout puts 4 CONSECUTIVE keys
// (quad*4+r) of one q-row (l16) in each lane -> P written as packed ds_write_b64
// straight into A-operand layout. K-frag LDS reads shared across both subtiles.
// Softmax: e = exp2(s + mask) via RAW v_exp_f32 (__builtin_amdgcn_exp2f);
// args bounded (|s|<~4), far from the subnormal guard range, so exact here.
// mask = L2E if key>qrow else 0, branchless cmp+cndmask.
// P packed to bf16 via v_cvt_pk_bf16_f32 (1 op/pair).
//
// ORDERING (rounds 3-6 saga): the P store->load same-wave dependence must be
// enforced WITHOUT global pinning. Proven mechanism (round 6, absmax OK):
//  (a) may_alias vector types on P accesses -> BasicAA sees the dependence on
//      the Ps object; (b) sched_barrier(0x7F) -> machine scheduler moves
//      ALU/MFMA/VMEM freely but no DS ops cross. Zero runtime instructions.
// REGISTER BUDGET (rounds 1/4/6 lesson): anything that extends live ranges
// past ~168 VGPR (launch_bounds 256,3) spills to scratch; spills show as
// FETCH/WRITE_SIZE blowup (VGPR_Count counter reads 84 regardless — do not
// trust it). The vreg[4][4] V-hoist (round 6) cost 64 live VGPRs -> 548 MB
// scratch writes. V fragments are therefore RE-READ from LDS per subtile
// (the 84-VGPR configuration of rounds 0/2/4).
// No online softmax (mask is +1.0 additive, scores bounded -> shift=0 exact).
__global__ __launch_bounds__(256, 3) void attn_win(const unsigned short* __restrict__ qk,
                                                   const unsigned short* __restrict__ Vt,
                                                   unsigned short* __restrict__ O,
                                                   int W) {
    const int nkt = W >> 7;
    const int tid = threadIdx.x, wv = tid >> 6, lane = tid & 63;
    const int quad = lane >> 4, l16 = lane & 15;

    // block remap (global path): keep the 8 q-blocks of one (window,head) on one XCD
    int wh, qb;
    if (nkt == 8) {
        const int g = blockIdx.x;
        wh = (g >> 6) * 8 + (g & 7);     // window*16+head
        qb = (g >> 3) & 7;
    } else {
        wh = blockIdx.x; qb = 0;
    }
    const int winst = wh >> 4, head = wh & 15;
    const size_t rw = (size_t)winst * W;

    __shared__ unsigned short Ks[128 * 64];     // [key][8 chunks, XOR-swizzled]
    __shared__ unsigned short Vs[64 * 128];     // V^T tile [dh][16 chunks, XOR-swizzled]
    __shared__ unsigned short Ps[4 * 16 * 136]; // per-wave P [16 q-rows][128 keys + 8 pad]
    unsigned short* Pw = Ps + wv * 16 * 136;

    // Q frags (B-operand layout: lane&15 = q-row, quad*8+j = k), reused all k-tiles
    v8s qf[2][2];
#pragma unroll
    for (int st = 0; st < 2; ++st) {
        const size_t qrow = rw + (size_t)(qb * 128 + wv * 32 + st * 16 + l16);
        const unsigned short* qp = qk + qrow * 2048 + head * 64 + quad * 8;
        qf[st][0] = *(const v8s*)qp;
        qf[st][1] = *(const v8s*)(qp + 32);
    }

    float rsum[2] = {0.f, 0.f};   // row sum for q-row l16 (partial over this lane's keys)
    v4f oacc[2][4] = {};          // O C-layout: col(dh)=l16, row(q)=quad*4+r

    for (int kt = 0; kt < nkt; ++kt) {
        __syncthreads();
#pragma unroll
        for (int j = 0; j < 4; ++j) {           // stage K tile: 128 keys x 64 dh
            const int cb = (wv * 4 + j) * 64;
            const int cl = cb + lane;
            const int key = cl >> 3, c = cl & 7;
            const unsigned short* src = qk + (rw + (size_t)(kt * 128 + key)) * 2048
                                        + 1024 + head * 64 + ((c ^ (key & 7)) * 8);
            __builtin_amdgcn_global_load_lds(
                (const __attribute__((address_space(1))) unsigned int*)src,
                (__attribute__((address_space(3))) unsigned int*)(Ks + cb * 8), 16, 0, 0);
        }
#pragma unroll
        for (int j = 0; j < 4; ++j) {           // stage V^T tile: 64 dh x 128 keys
            const int cb = (wv * 4 + j) * 64;
            const int cl = cb + lane;
            const int dh = cl >> 4, c = cl & 15;
            const unsigned short* src = Vt + (size_t)(head * 64 + dh) * 16384
                                        + rw + (size_t)(kt * 128) + ((c ^ (dh & 7)) * 8);
            __builtin_amdgcn_global_load_lds(
                (const __attribute__((address_space(1))) unsigned int*)src,
                (__attribute__((address_space(3))) unsigned int*)(Vs + cb * 8), 16, 0, 0);
        }
        __syncthreads();

        // S^T for both subtiles, sharing every K-frag read
        v4f sf[2][8] = {};
#pragma unroll
        for (int nt = 0; nt < 8; ++nt) {
            const int krow = nt * 16 + l16;
#pragma unroll
            for (int ks = 0; ks < 2; ++ks) {
                const v8s kf = *(const v8s*)(Ks + krow * 64 + ((ks * 4 + quad) ^ (krow & 7)) * 8);
                sf[0][nt] = __builtin_amdgcn_mfma_f32_16x16x32_bf16(kf, qf[0][ks], sf[0][nt], 0, 0, 0);
                sf[1][nt] = __builtin_amdgcn_mfma_f32_16x16x32_bf16(kf, qf[1][ks], sf[1][nt], 0, 0, 0);
            }
        }

#pragma unroll
        for (int st = 0; st < 2; ++st) {
            const int irow = qb * 128 + wv * 32 + st * 16 + l16;   // this lane's q-row
            float rl = 0.f;
#pragma unroll
            for (int nt = 0; nt < 8; ++nt) {
                const int jb = kt * 128 + nt * 16 + quad * 4;      // first key in this lane's 4
                float e[4];
#pragma unroll
                for (int r = 0; r < 4; ++r)
                    e[r] = __builtin_amdgcn_exp2f(sf[st][nt][r] + ((jb + r > irow) ? L2E : 0.0f));
                rl += (e[0] + e[1]) + (e[2] + e[3]);
                union { uint32_t u[2]; v4s_a s; } pu;
                pu.u[0] = cvt_pk_bf16(e[0], e[1]);
                pu.u[1] = cvt_pk_bf16(e[2], e[3]);
                *(v4s_a*)(Pw + l16 * 136 + nt * 16 + quad * 4) = pu.s;   // ds_write_b64
            }
            rsum[st] += rl;
            // fence: DS ops may not cross (P stores stay above P loads);
            // ALU/MFMA/VMEM flow freely.
            __builtin_amdgcn_sched_barrier(SCHED_NO_DS);
            // O += P V  (P read back in A-layout via may_alias type: true
            // dependence on the P stores above is visible to alias analysis)
#pragma unroll
            for (int kk = 0; kk < 4; ++kk) {
                const v8s pf = (v8s)(*(const v8s_a*)(Pw + l16 * 136 + kk * 32 + quad * 8));
#pragma unroll
                for (int dt = 0; dt < 4; ++dt) {
                    const int dh = dt * 16 + l16;
                    const v8s vf = *(const v8s*)(Vs + dh * 128 + ((kk * 4 + quad) ^ (dh & 7)) * 8);
                    oacc[st][dt] = __builtin_amdgcn_mfma_f32_16x16x32_bf16(pf, vf, oacc[st][dt], 0, 0, 0);
                }
            }
            // fence: next subtile's / k-tile's P stores may not hoist above these loads.
            __builtin_amdgcn_sched_barrier(SCHED_NO_DS);
        }
    }

    // reduce row sums across quads (row = l16), redistribute to C-layout rows, store
#pragma unroll
    for (int st = 0; st < 2; ++st) {
        float l = rsum[st];
        l += __shfl_xor(l, 16);
        l += __shfl_xor(l, 32);
        const float inv = 1.0f / l;              // inverse sum for q-row l16
#pragma unroll
        for (int r = 0; r < 4; ++r) {
            const float invr = __shfl(inv, quad * 4 + r);   // row quad*4+r's inverse
            const size_t row = rw + (size_t)(qb * 128 + wv * 32 + st * 16 + quad * 4 + r);
#pragma unroll
            for (int dt = 0; dt < 4; ++dt)
                O[row * 1024 + head * 64 + dt * 16 + l16] = f2bf(oacc[st][dt][r] * invr);
        }
    }
}

// ---------------- launcher ----------------
extern "C" void kernel_launch(void* const* d_in, const int* in_sizes, int n_in,
                              void* d_out, int out_size, void* d_ws, size_t ws_size,
                              hipStream_t stream) {
    const float* lqs    = (const float*)d_in[0];
    const float* gqs    = (const float*)d_in[1];
    const float* wl_in  = (const float*)d_in[2];
    const float* bl_in  = (const float*)d_in[3];
    const float* wl_out = (const float*)d_in[4];
    const float* bl_out = (const float*)d_in[5];
    const float* wg_in  = (const float*)d_in[6];
    const float* bg_in  = (const float*)d_in[7];
    const float* wg_out = (const float*)d_in[8];
    const float* bg_out = (const float*)d_in[9];

    char* ws = (char*)d_ws;                                       // total 176,160,768 B
    unsigned short* Xbf    = (unsigned short*)(ws);               // 33,554,432
    unsigned short* Obf    = (unsigned short*)(ws + 33554432);    // 33,554,432
    unsigned short* Winbf  = (unsigned short*)(ws + 67108864);    //  6,291,456
    unsigned short* Woutbf = (unsigned short*)(ws + 73400320);    //  2,097,152
    unsigned short* QKbf   = (unsigned short*)(ws + 75497472);    // 67,108,864  [R][2048]
    unsigned short* Vtbf   = (unsigned short*)(ws + 142606336);   // 33,554,432  [1024][R]

    const int R = 4 * 4096;   // 16384 rows (windows tile S contiguously)
    const int D = 1024;

    for (int path = 0; path < 2; ++path) {
        const float* x     = path == 0 ? lqs : gqs;
        const float* w_in  = path == 0 ? wl_in : wg_in;
        const float* b_in  = path == 0 ? bl_in : bg_in;
        const float* w_out = path == 0 ? wl_out : wg_out;
        const float* b_out = path == 0 ? bl_out : bg_out;
        const int W        = path == 0 ? 128 : 1024;
        float* outp = (float*)d_out + (size_t)path * R * D;

        hipLaunchKernelGGL(cast_f32_bf16, dim3(4096), dim3(256), 0, stream, x, Xbf, R * D);
        hipLaunchKernelGGL(cast_f32_bf16, dim3(3072), dim3(256), 0, stream, w_in, Winbf, 3 * D * D);
        hipLaunchKernelGGL(cast_f32_bf16, dim3(1024), dim3(256), 0, stream, w_out, Woutbf, D * D);
        // QKV projection: Q|K row-major (ldc=2048, Q pre-scaled), V transposed into Vtbf
        hipLaunchKernelGGL((gemm_nt<false, true>), dim3(128 * 24), dim3(256), 0, stream,
                           Xbf, Winbf, b_in, (void*)QKbf, Vtbf, R, 3 * D, D, 2048);
        hipLaunchKernelGGL(attn_win, dim3(2048), dim3(256), 0, stream, QKbf, Vtbf, Obf, W);
        // output projection -> fp32 d_out
        hipLaunchKernelGGL((gemm_nt<true, false>), dim3(128 * 8), dim3(256), 0, stream,
                           Obf, Woutbf, b_out, (void*)outp, (unsigned short*)nullptr,
                           R, D, D, 1024);
    }
}

// Round 8
// 703.876 us; speedup vs baseline: 1.3917x; 1.1424x over previous
//
#include <hip/hip_runtime.h>
#include <stdint.h>

typedef short v8s __attribute__((ext_vector_type(8)));    // 8 bf16 (4 VGPRs)
typedef float v4f __attribute__((ext_vector_type(4)));    // 16x16 C/D frag
typedef float f32x16 __attribute__((ext_vector_type(16))); // 32x32 C/D frag

__device__ __forceinline__ unsigned short f2bf(float f) {
    union { float f; uint32_t u; } x; x.f = f;
    uint32_t r = (x.u + 0x7fffu + ((x.u >> 16) & 1u)) >> 16;
    return (unsigned short)r;
}
// packed f32x2 -> bf16x2 in one VALU op (gfx950 v_cvt_pk_bf16_f32, RNE)
__device__ __forceinline__ uint32_t cvt_pk_bf16(float lo, float hi) {
    uint32_t r;
    asm("v_cvt_pk_bf16_f32 %0, %1, %2" : "=v"(r) : "v"(lo), "v"(hi));
    return r;
}

#define QSCALE 0.18033688011112042f   /* 0.125 * log2(e) */
#define L2E    1.4426950408889634f    /* log2(e) — mask adds +1.0 to logits */

// ---------------- fp32 -> bf16 cast (memory-bound) ----------------
__global__ __launch_bounds__(256) void cast_f32_bf16(const float* __restrict__ in,
                                                     unsigned short* __restrict__ out, int n) {
    int i = (blockIdx.x * 256 + threadIdx.x) * 4;
    const int stride = gridDim.x * 256 * 4;
    for (; i < n; i += stride) {
        float4 v = *(const float4*)(in + i);
        ushort4 o;
        o.x = f2bf(v.x); o.y = f2bf(v.y); o.z = f2bf(v.z); o.w = f2bf(v.w);
        *(ushort4*)(out + i) = o;
    }
}

// ---------------- NT GEMM: C[M,N] = A[M,K] * B[N,K]^T + bias ----------------
// (unchanged from round 7 — proven)
template <bool OUT_F32, bool VSPLIT>
__global__ __launch_bounds__(256) void gemm_nt(const unsigned short* __restrict__ A,
                                               const unsigned short* __restrict__ B,
                                               const float* __restrict__ bias,
                                               void* __restrict__ Cout,
                                               unsigned short* __restrict__ vt,
                                               int M, int N, int K, int ldc) {
    __shared__ unsigned short As[128 * 64];
    __shared__ unsigned short Bs[128 * 64];
    const int tid = threadIdx.x;
    const int wv = tid >> 6, lane = tid & 63;
    const int quad = lane >> 4, l16 = lane & 15;
    const int tiles_n = N >> 7;
    const int tm = blockIdx.x / tiles_n, tn = blockIdx.x - tm * tiles_n;
    const int m0 = tm << 7, n0 = tn << 7;
    const int wr = (wv >> 1) * 64, wc = (wv & 1) * 64;

    v4f acc[4][4] = {};

    for (int k0 = 0; k0 < K; k0 += 64) {
        __syncthreads();
#pragma unroll
        for (int j = 0; j < 4; ++j) {
            const int cb = (wv * 4 + j) * 64;
            const int cl = cb + lane;
            const int row = cl >> 3;
            const int kc = (cl & 7) ^ (row & 7);
            const unsigned short* ga = A + (size_t)(m0 + row) * K + k0 + kc * 8;
            const unsigned short* gb = B + (size_t)(n0 + row) * K + k0 + kc * 8;
            __builtin_amdgcn_global_load_lds(
                (const __attribute__((address_space(1))) unsigned int*)ga,
                (__attribute__((address_space(3))) unsigned int*)(As + cb * 8), 16, 0, 0);
            __builtin_amdgcn_global_load_lds(
                (const __attribute__((address_space(1))) unsigned int*)gb,
                (__attribute__((address_space(3))) unsigned int*)(Bs + cb * 8), 16, 0, 0);
        }
        __syncthreads();
#pragma unroll
        for (int ks = 0; ks < 2; ++ks) {
            v8s af[4], bf[4];
#pragma unroll
            for (int mt = 0; mt < 4; ++mt) {
                const int row = wr + mt * 16 + l16;
                const int ch = row * 8 + ((ks * 4 + quad) ^ (row & 7));
                af[mt] = *(const v8s*)(As + ch * 8);
            }
#pragma unroll
            for (int nt = 0; nt < 4; ++nt) {
                const int row = wc + nt * 16 + l16;
                const int ch = row * 8 + ((ks * 4 + quad) ^ (row & 7));
                bf[nt] = *(const v8s*)(Bs + ch * 8);
            }
#pragma unroll
            for (int mt = 0; mt < 4; ++mt)
#pragma unroll
                for (int nt = 0; nt < 4; ++nt)
                    acc[mt][nt] = __builtin_amdgcn_mfma_f32_16x16x32_bf16(
                        af[mt], bf[nt], acc[mt][nt], 0, 0, 0);
        }
    }
#pragma unroll
    for (int nt = 0; nt < 4; ++nt) {
        const int col = n0 + wc + nt * 16 + l16;
        const float bv = bias[col];
        if (VSPLIT && col >= 2048) {
#pragma unroll
            for (int mt = 0; mt < 4; ++mt) {
                const int rowb = m0 + wr + mt * 16 + quad * 4;
                ushort4 o;
                o.x = f2bf(acc[mt][nt][0] + bv);
                o.y = f2bf(acc[mt][nt][1] + bv);
                o.z = f2bf(acc[mt][nt][2] + bv);
                o.w = f2bf(acc[mt][nt][3] + bv);
                *(ushort4*)(vt + (size_t)(col - 2048) * M + rowb) = o;
            }
        } else {
            const float scl = (VSPLIT && col < 1024) ? QSCALE : 1.0f;
#pragma unroll
            for (int mt = 0; mt < 4; ++mt) {
                const int rowb = m0 + wr + mt * 16 + quad * 4;
#pragma unroll
                for (int r = 0; r < 4; ++r) {
                    if (OUT_F32)
                        ((float*)Cout)[(size_t)(rowb + r) * ldc + col] = acc[mt][nt][r] + bv;
                    else
                        ((unsigned short*)Cout)[(size_t)(rowb + r) * ldc + col] =
                            f2bf((acc[mt][nt][r] + bv) * scl);
                }
            }
        }
    }
}

// ---------------- windowed attention, 32x32x16 MFMA, register-only P ----------------
// qk: [R,2048] bf16 (Q(pre-scaled by 0.125*log2e)|K). Vt: [1024][R] bf16 (V^T).
// O: [R,1024] bf16.
// Block = (window, head, 128-row q-block); each wave owns 32 q-rows.
// S^T = K*Q^T via mfma_32x32x16 (A=K: lane&31=key, k=(lane>>5)*8+j;
// B=Q: lane&31=q). C-layout (m74/m101): col=lane&31=q, row=(r&3)+8(r>>2)+4*hi=key.
// => each lane holds P for ITS OWN q-row (=l32); the PV A-operand (lane&31=q,
// k-slot=hi*8+j) needs only a lane<->lane+32 exchange: v_permlane32_swap_b32
// (VALU). Per 16-key group: wA=pk(e0,e1) wB=pk(e4,e5) wC=pk(e2,e3) wD=pk(e6,e7);
// swap(wA,wB) -> (w01|w89),(w45|w12_13); swap(wC,wD) -> (w23|w10_11),(w67|w14_15);
// frag = [wA,wC,wB,wD]. This DELETES the P LDS round-trip (rounds 3-7's hazard
// class is structurally gone: pure register dataflow, no fences needed), frees
// the Ps buffer (LDS 50->32 KB), and halves DS traffic (32 ds_read_b128/kt/wave:
// 16 K + 16 V; one 32-wide V B-frag serves the whole wave, no subtile re-read).
// Softmax: e = exp2(s + mask) via raw v_exp_f32 (proven r4/r7); mask select
// branchless vs precomputed thr = irow - 4*hi. Shift=0 exact (scores bounded).
// Fused per-key-group (QK -> softmax -> pack -> PV) keeps peak VGPR ~110.
__global__ __launch_bounds__(256, 3) void attn_win(const unsigned short* __restrict__ qk,
                                                   const unsigned short* __restrict__ Vt,
                                                   unsigned short* __restrict__ O,
                                                   int W) {
    const int nkt = W >> 7;
    const int tid = threadIdx.x, wv = tid >> 6, lane = tid & 63;
    const int hi = lane >> 5, l32 = lane & 31;

    // block remap (global path): keep the 8 q-blocks of one (window,head) on one XCD
    int wh, qb;
    if (nkt == 8) {
        const int g = blockIdx.x;
        wh = (g >> 6) * 8 + (g & 7);     // window*16+head
        qb = (g >> 3) & 7;
    } else {
        wh = blockIdx.x; qb = 0;
    }
    const int winst = wh >> 4, head = wh & 15;
    const size_t rw = (size_t)winst * W;

    __shared__ unsigned short Ks[128 * 64];     // [key][8 dh-chunks, XOR-swizzled]
    __shared__ unsigned short Vs[64 * 128];     // [dh][16 key-chunks, XOR-swizzled]

    const int irow = qb * 128 + wv * 32 + l32;  // this lane's q-row (window-relative)
    const int thr  = irow - 4 * hi;             // mask: key > irow <=> kx > thr

    // Q frags (B-operand: lane&31 = q-row, k = hi*8+j), 4 k-steps of dh16
    v8s qf[4];
    {
        const size_t qrow = rw + (size_t)irow;
        const unsigned short* qp = qk + qrow * 2048 + head * 64 + hi * 8;
#pragma unroll
        for (int ks = 0; ks < 4; ++ks) qf[ks] = *(const v8s*)(qp + ks * 16);
    }

    float rsum = 0.f;
    f32x16 oacc[2] = {};   // O C-layout: col=l32=dh (per 32-group), row r = q-within-32

    for (int kt = 0; kt < nkt; ++kt) {
        __syncthreads();
#pragma unroll
        for (int j = 0; j < 4; ++j) {           // stage K tile: 128 keys x 64 dh
            const int cb = (wv * 4 + j) * 64;
            const int cl = cb + lane;
            const int key = cl >> 3, c = cl & 7;
            const unsigned short* src = qk + (rw + (size_t)(kt * 128 + key)) * 2048
                                        + 1024 + head * 64 + ((c ^ (key & 7)) * 8);
            __builtin_amdgcn_global_load_lds(
                (const __attribute__((address_space(1))) unsigned int*)src,
                (__attribute__((address_space(3))) unsigned int*)(Ks + cb * 8), 16, 0, 0);
        }
#pragma unroll
        for (int j = 0; j < 4; ++j) {           // stage V^T tile: 64 dh x 128 keys
            const int cb = (wv * 4 + j) * 64;
            const int cl = cb + lane;
            const int dh = cl >> 4, c = cl & 15;
            const unsigned short* src = Vt + (size_t)(head * 64 + dh) * 16384
                                        + rw + (size_t)(kt * 128) + ((c ^ (dh & 7)) * 8);
            __builtin_amdgcn_global_load_lds(
                (const __attribute__((address_space(1))) unsigned int*)src,
                (__attribute__((address_space(3))) unsigned int*)(Vs + cb * 8), 16, 0, 0);
        }
        __syncthreads();

#pragma unroll
        for (int kg = 0; kg < 4; ++kg) {        // 32 keys per group
            // S^T for this key-group (accumulate over dh in 4 k-steps)
            f32x16 s = {};
            const int key0 = kg * 32 + l32;
#pragma unroll
            for (int ks = 0; ks < 4; ++ks) {
                const v8s kf = *(const v8s*)(Ks + key0 * 64
                                             + (((ks << 1) | hi) ^ (key0 & 7)) * 8);
                s = __builtin_amdgcn_mfma_f32_32x32x16_bf16(kf, qf[ks], s, 0, 0, 0);
            }
            // softmax (this lane's 16 of the 32 keys, all for q-row l32)
            const int kb = kt * 128 + kg * 32;
            float e[16];
#pragma unroll
            for (int r = 0; r < 16; ++r) {
                const int kx = kb + (r & 3) + 8 * (r >> 2);   // +4*hi folded into thr
                e[r] = __builtin_amdgcn_exp2f(s[r] + ((kx > thr) ? L2E : 0.0f));
            }
            rsum += (((e[0] + e[1]) + (e[2] + e[3])) + ((e[4] + e[5]) + (e[6] + e[7])))
                  + (((e[8] + e[9]) + (e[10] + e[11])) + ((e[12] + e[13]) + (e[14] + e[15])));
            // pack P to bf16 A-frags in-register (cvt_pk + permlane32_swap) + PV
#pragma unroll
            for (int h = 0; h < 2; ++h) {       // 16-key subgroup
                uint32_t wA = cvt_pk_bf16(e[8 * h + 0], e[8 * h + 1]);
                uint32_t wB = cvt_pk_bf16(e[8 * h + 4], e[8 * h + 5]);
                uint32_t wC = cvt_pk_bf16(e[8 * h + 2], e[8 * h + 3]);
                uint32_t wD = cvt_pk_bf16(e[8 * h + 6], e[8 * h + 7]);
                asm("v_permlane32_swap_b32 %0, %1" : "+v"(wA), "+v"(wB));
                asm("v_permlane32_swap_b32 %0, %1" : "+v"(wC), "+v"(wD));
                union { uint32_t u[4]; v8s s8; } pa;
                pa.u[0] = wA; pa.u[1] = wC; pa.u[2] = wB; pa.u[3] = wD;
                const int c0 = kg * 4 + h * 2 + hi;   // 16-chunk index into 128 keys
#pragma unroll
                for (int dhg = 0; dhg < 2; ++dhg) {
                    const int dh = dhg * 32 + l32;
                    const v8s vf = *(const v8s*)(Vs + dh * 128 + ((c0 ^ (dh & 7))) * 8);
                    oacc[dhg] = __builtin_amdgcn_mfma_f32_32x32x16_bf16(
                        pa.s8, vf, oacc[dhg], 0, 0, 0);
                }
            }
        }
    }

    // rsum: lane has the partial for q=l32 over its hi-half keys; combine halves
    const float tot = rsum + __shfl_xor(rsum, 32);
    const float inv = 1.0f / tot;
#pragma unroll
    for (int r = 0; r < 16; ++r) {
        const int q32 = (r & 3) + 8 * (r >> 2) + 4 * hi;   // q-row within 32
        const float invr = __shfl(inv, q32 + (hi << 5));   // inv lives on lane q32 (both halves)
        const size_t row = rw + (size_t)(qb * 128 + wv * 32 + q32);
#pragma unroll
        for (int dhg = 0; dhg < 2; ++dhg)
            O[row * 1024 + head * 64 + dhg * 32 + l32] = f2bf(oacc[dhg][r] * invr);
    }
}

// ---------------- launcher ----------------
extern "C" void kernel_launch(void* const* d_in, const int* in_sizes, int n_in,
                              void* d_out, int out_size, void* d_ws, size_t ws_size,
                              hipStream_t stream) {
    const float* lqs    = (const float*)d_in[0];
    const float* gqs    = (const float*)d_in[1];
    const float* wl_in  = (const float*)d_in[2];
    const float* bl_in  = (const float*)d_in[3];
    const float* wl_out = (const float*)d_in[4];
    const float* bl_out = (const float*)d_in[5];
    const float* wg_in  = (const float*)d_in[6];
    const float* bg_in  = (const float*)d_in[7];
    const float* wg_out = (const float*)d_in[8];
    const float* bg_out = (const float*)d_in[9];

    char* ws = (char*)d_ws;                                       // total 176,160,768 B
    unsigned short* Xbf    = (unsigned short*)(ws);               // 33,554,432
    unsigned short* Obf    = (unsigned short*)(ws + 33554432);    // 33,554,432
    unsigned short* Winbf  = (unsigned short*)(ws + 67108864);    //  6,291,456
    unsigned short* Woutbf = (unsigned short*)(ws + 73400320);    //  2,097,152
    unsigned short* QKbf   = (unsigned short*)(ws + 75497472);    // 67,108,864  [R][2048]
    unsigned short* Vtbf   = (unsigned short*)(ws + 142606336);   // 33,554,432  [1024][R]

    const int R = 4 * 4096;   // 16384 rows (windows tile S contiguously)
    const int D = 1024;

    for (int path = 0; path < 2; ++path) {
        const float* x     = path == 0 ? lqs : gqs;
        const float* w_in  = path == 0 ? wl_in : wg_in;
        const float* b_in  = path == 0 ? bl_in : bg_in;
        const float* w_out = path == 0 ? wl_out : wg_out;
        const float* b_out = path == 0 ? bl_out : bg_out;
        const int W        = path == 0 ? 128 : 1024;
        float* outp = (float*)d_out + (size_t)path * R * D;

        hipLaunchKernelGGL(cast_f32_bf16, dim3(4096), dim3(256), 0, stream, x, Xbf, R * D);
        hipLaunchKernelGGL(cast_f32_bf16, dim3(3072), dim3(256), 0, stream, w_in, Winbf, 3 * D * D);
        hipLaunchKernelGGL(cast_f32_bf16, dim3(1024), dim3(256), 0, stream, w_out, Woutbf, D * D);
        // QKV projection: Q|K row-major (ldc=2048, Q pre-scaled), V transposed into Vtbf
        hipLaunchKernelGGL((gemm_nt<false, true>), dim3(128 * 24), dim3(256), 0, stream,
                           Xbf, Winbf, b_in, (void*)QKbf, Vtbf, R, 3 * D, D, 2048);
        hipLaunchKernelGGL(attn_win, dim3(2048), dim3(256), 0, stream, QKbf, Vtbf, Obf, W);
        // output projection -> fp32 d_out
        hipLaunchKernelGGL((gemm_nt<true, false>), dim3(128 * 8), dim3(256), 0, stream,
                           Obf, Woutbf, b_out, (void*)outp, (unsigned short*)nullptr,
                           R, D, D, 1024);
    }
}